// Round 1
// baseline (316.730 us; speedup 1.0000x reference)
//
#include <hip/hip_runtime.h>
#include <math.h>

// ProbAttention (Informer ProbSparse) — B=8 L=2048 H=8 D=64 u=40
// q/k/v reshape(B,H,L,D) is a flat reinterpretation -> treat as (BH=64, L, D) contiguous.
#define LSEQ 2048
#define DDIM 64
#define UU   40
#define NBH  64
#define CTX_ELEMS (NBH*UU*DDIM)   // 163840

// ---------------- K12 v2: fused QK_sample + M, 8-lanes-per-l geometry ----------------
// 4096 blocks: bh = b&63, ltile = b>>6 (32 l per block). Thread = (g = t>>3, sub = t&7).
// Each 8-lane group reads a gathered k-row as two FULL 128B cache lines:
//   kr4[sub]   -> bytes [0,128)   (one line, consumed entirely by ONE instruction)
//   kr4[sub+8] -> bytes [128,256) (the other line)
// The old 4-lane 64B-slice pattern needed L1 temporal hits (m=0 fetch, m=1 hit) that
// ~22 concurrent waves thrash out of the 32KB L1 -> every 64B slice became an L2 fill.
// This version makes every fetched line fully used by its own instruction and halves
// the divergent-segment count per TA lookup (8 lines/inst vs 16).
__global__ __launch_bounds__(256, 4) void k12_sample_m(
    const float* __restrict__ q, const float* __restrict__ k,
    const int* __restrict__ idxs, float* __restrict__ M) {
  int b = blockIdx.x;
  int bh = b & 63;
  int ltile = b >> 6;
  int t = threadIdx.x;
  int g = t >> 3;
  int sub = t & 7;
  int l = ltile * 32 + g;

  const float4* qr = (const float4*)(q + (size_t)(bh * LSEQ + l) * DDIM);
  float4 qa = qr[sub];       // floats [sub*4 .. sub*4+4)       (line 0 of row)
  float4 qb = qr[sub + 8];   // floats [32+sub*4 .. 32+sub*4+4) (line 1 of row)

  const float* kbase = k + (size_t)bh * LSEQ * DDIM;
  const int4* ir = (const int4*)(idxs + l * UU);

  float mx = -INFINITY, sm = 0.f;
#pragma unroll 1
  for (int s4 = 0; s4 < UU / 4; ++s4) {
    int4 jv = ir[s4];
    const float4* k0 = (const float4*)(kbase + (size_t)jv.x * DDIM);
    const float4* k1 = (const float4*)(kbase + (size_t)jv.y * DDIM);
    const float4* k2 = (const float4*)(kbase + (size_t)jv.z * DDIM);
    const float4* k3 = (const float4*)(kbase + (size_t)jv.w * DDIM);
    float4 a0 = k0[sub], b0 = k0[sub + 8];
    float4 a1 = k1[sub], b1 = k1[sub + 8];
    float4 a2 = k2[sub], b2 = k2[sub + 8];
    float4 a3 = k3[sub], b3 = k3[sub + 8];
    float d0 = qa.x * a0.x + qa.y * a0.y + qa.z * a0.z + qa.w * a0.w
             + qb.x * b0.x + qb.y * b0.y + qb.z * b0.z + qb.w * b0.w;
    float d1 = qa.x * a1.x + qa.y * a1.y + qa.z * a1.z + qa.w * a1.w
             + qb.x * b1.x + qb.y * b1.y + qb.z * b1.z + qb.w * b1.w;
    float d2 = qa.x * a2.x + qa.y * a2.y + qa.z * a2.z + qa.w * a2.w
             + qb.x * b2.x + qb.y * b2.y + qb.z * b2.z + qb.w * b2.w;
    float d3 = qa.x * a3.x + qa.y * a3.y + qa.z * a3.z + qa.w * a3.w
             + qb.x * b3.x + qb.y * b3.y + qb.z * b3.z + qb.w * b3.w;
    // 8-lane butterfly reduce (xor bits 0..2 stay inside the group)
    d0 += __shfl_xor(d0, 1, 64); d0 += __shfl_xor(d0, 2, 64); d0 += __shfl_xor(d0, 4, 64);
    d1 += __shfl_xor(d1, 1, 64); d1 += __shfl_xor(d1, 2, 64); d1 += __shfl_xor(d1, 4, 64);
    d2 += __shfl_xor(d2, 1, 64); d2 += __shfl_xor(d2, 2, 64); d2 += __shfl_xor(d2, 4, 64);
    d3 += __shfl_xor(d3, 1, 64); d3 += __shfl_xor(d3, 2, 64); d3 += __shfl_xor(d3, 4, 64);
    mx = fmaxf(fmaxf(fmaxf(mx, d0), fmaxf(d1, d2)), d3);
    sm += (d0 + d1) + (d2 + d3);   // same accumulation order as passing baseline
  }
  if (sub == 0) M[bh * LSEQ + l] = mx - sm * (1.0f / (float)LSEQ);
}

// ---------------- K3: top-40 per head; M in regs, shfl + LDS reduce ----------------
// desc value, tie -> smaller index (matches jax.lax.top_k stability)
// Fix vs v1: winner clear uses statically-indexed predicated writes (runtime-indexed
// v[wi>>8] demotes the array to scratch — rule #20).
__global__ __launch_bounds__(256) void k3_topk(const float* __restrict__ M,
                                               int* __restrict__ Mtop) {
  int bh = blockIdx.x;
  int t = threadIdx.x;
  int w = t >> 6;
  int lane = t & 63;
  float v[8];
#pragma unroll
  for (int j = 0; j < 8; ++j) v[j] = M[bh * LSEQ + t + 256 * j];
  __shared__ float swv[4];
  __shared__ int   swi[4];
  __shared__ int   win;
  for (int it = 0; it < UU; ++it) {
    float bv = -INFINITY; int bi = 0x7fffffff;
#pragma unroll
    for (int j = 0; j < 8; ++j) {
      if (v[j] > bv) { bv = v[j]; bi = t + 256 * j; }
    }
#pragma unroll
    for (int off = 32; off > 0; off >>= 1) {
      float ov = __shfl_xor(bv, off, 64);
      int   oi = __shfl_xor(bi, off, 64);
      if (ov > bv || (ov == bv && oi < bi)) { bv = ov; bi = oi; }
    }
    if (lane == 0) { swv[w] = bv; swi[w] = bi; }
    __syncthreads();
    if (t == 0) {
      float fv = swv[0]; int fi = swi[0];
#pragma unroll
      for (int j = 1; j < 4; ++j) {
        if (swv[j] > fv || (swv[j] == fv && swi[j] < fi)) { fv = swv[j]; fi = swi[j]; }
      }
      Mtop[bh * UU + it] = fi;
      win = fi;
    }
    __syncthreads();
    int wi = win;
#pragma unroll
    for (int j = 0; j < 8; ++j)
      if (wi == t + 256 * j) v[j] = -INFINITY;   // static index, predicated
  }
}

// ---------------- K45: fused scores + softmax -> normalized attn ----------------
// 640 blocks: bh = b&63, ug = b>>6 (4 u each). 32KB LDS -> 4 blocks/CU capacity.
// Scores now use the same 8-lanes-per-l geometry as k12: each group consumes k rows
// as whole 128B lines in single instructions (no L1 temporal-hit reliance while
// streaming 512KB of k per block through a thrashed shared L1).
// Softmax: wave w owns row u=w (full 2048 in LDS, pure shfl reduce).
// Also zeroes ctx (640*256 == CTX_ELEMS exactly) for k7's atomics.
__global__ __launch_bounds__(256, 4) void k45_scores_softmax(
    const float* __restrict__ q, const float* __restrict__ k,
    const int* __restrict__ Mtop, float* __restrict__ attn,
    float* __restrict__ ctx) {
  __shared__ float sct[4 * LSEQ];    // 32KB, [u][l]
  int b = blockIdx.x;
  int bh = b & 63;
  int u0 = (b >> 6) * 4;
  int t = threadIdx.x;
  int g = t >> 3;
  int sub = t & 7;

  ctx[b * 256 + t] = 0.f;

  float4 qa[4], qb[4];
#pragma unroll
  for (int u = 0; u < 4; ++u) {
    int qi = Mtop[bh * UU + u0 + u];
    const float4* qr = (const float4*)(q + (size_t)(bh * LSEQ + qi) * DDIM);
    qa[u] = qr[sub];
    qb[u] = qr[sub + 8];
  }

  const float* kb = k + (size_t)bh * LSEQ * DDIM;
#pragma unroll 1
  for (int p = 0; p < 64; ++p) {
    int l = p * 32 + g;
    const float4* kr = (const float4*)(kb + (size_t)l * DDIM);
    float4 ka = kr[sub];       // line 0 of row l
    float4 kc = kr[sub + 8];   // line 1 of row l
#pragma unroll
    for (int u = 0; u < 4; ++u) {
      float s = qa[u].x * ka.x + qa[u].y * ka.y + qa[u].z * ka.z + qa[u].w * ka.w
              + qb[u].x * kc.x + qb[u].y * kc.y + qb[u].z * kc.z + qb[u].w * kc.w;
      s += __shfl_xor(s, 1, 64);
      s += __shfl_xor(s, 2, 64);
      s += __shfl_xor(s, 4, 64);
      if (sub == 0) sct[u * LSEQ + l] = s * 0.125f;
    }
  }
  __syncthreads();

  // softmax: wave w owns row w
  int w = t >> 6, lane = t & 63;
  float* row = sct + w * LSEQ;
  float vv[32];
  float mx = -INFINITY;
#pragma unroll
  for (int j = 0; j < 32; ++j) { vv[j] = row[lane + 64 * j]; mx = fmaxf(mx, vv[j]); }
#pragma unroll
  for (int off = 32; off > 0; off >>= 1) mx = fmaxf(mx, __shfl_xor(mx, off, 64));
  float sm = 0.f;
#pragma unroll
  for (int j = 0; j < 32; ++j) { vv[j] = __expf(vv[j] - mx); sm += vv[j]; }
#pragma unroll
  for (int off = 32; off > 0; off >>= 1) sm += __shfl_xor(sm, off, 64);
  float inv = 1.0f / sm;
  float* ap = attn + (size_t)(bh * UU + u0 + w) * LSEQ;
#pragma unroll
  for (int j = 0; j < 32; ++j) ap[lane + 64 * j] = vv[j] * inv;
}

// ---------------- K7: context[bh,u,d] += sum_l attn[bh,u,l] * v[bh,l,d] ----------------
// 512 blocks: bh = b&63, l-eighth = b>>6 (256 l). v tile staged in 64KB LDS once;
// wave w owns u-group w*10..w*10+10 (attn rows read once per block, broadcast loads).
// fp32 atomicAdd into ctx (zeroed by k45).
__global__ __launch_bounds__(256) void k7_context(
    const float* __restrict__ attn, const float* __restrict__ v,
    float* __restrict__ ctx) {
  __shared__ float vt[256 * DDIM];   // 64KB
  int b = blockIdx.x;
  int bh = b & 63;
  int l0 = (b >> 6) * 256;
  int t = threadIdx.x;

  const float4* src = (const float4*)(v + ((size_t)bh * LSEQ + l0) * DDIM);
  float4* dst = (float4*)vt;
#pragma unroll
  for (int i = 0; i < 16; ++i) dst[t + 256 * i] = src[t + 256 * i];
  __syncthreads();

  int w = t >> 6;
  int d = t & 63;
  const float* ab = attn + ((size_t)bh * UU + w * 10) * LSEQ + l0;
  float acc[10];
#pragma unroll
  for (int u = 0; u < 10; ++u) acc[u] = 0.f;
#pragma unroll 1
  for (int l4 = 0; l4 < 64; ++l4) {
    int l = l4 * 4;
    float4 av[10];
#pragma unroll
    for (int u = 0; u < 10; ++u)
      av[u] = *(const float4*)(ab + (size_t)u * LSEQ + l);   // 64 lanes same addr -> broadcast
#pragma unroll
    for (int i = 0; i < 4; ++i) {
      float vvv = vt[(l + i) * DDIM + d];
#pragma unroll
      for (int u = 0; u < 10; ++u)
        acc[u] = fmaf(((const float*)&av[u])[i], vvv, acc[u]);
    }
  }
#pragma unroll
  for (int u = 0; u < 10; ++u)
    atomicAdd(&ctx[((size_t)bh * UU + w * 10 + u) * DDIM + d], acc[u]);
}

extern "C" void kernel_launch(void* const* d_in, const int* in_sizes, int n_in,
                              void* d_out, int out_size, void* d_ws, size_t ws_size,
                              hipStream_t stream) {
  const float* q   = (const float*)d_in[0];
  const float* k   = (const float*)d_in[1];
  const float* v   = (const float*)d_in[2];
  const int*   idx = (const int*)d_in[3];

  float* ctx  = (float*)d_out;                  // [NBH, UU, DDIM]
  float* attn = (float*)d_out + CTX_ELEMS;      // [NBH, UU, LSEQ]

  float* M    = (float*)d_ws;                                    // 131072 f
  int*   Mtop = (int*)(M + NBH * LSEQ);                          // 2560 i

  k12_sample_m<<<NBH * 64, 256, 0, stream>>>(q, k, idx, M);
  k3_topk<<<NBH, 256, 0, stream>>>(M, Mtop);
  k45_scores_softmax<<<NBH * 10, 256, 0, stream>>>(q, k, Mtop, attn, ctx);
  k7_context<<<NBH * 8, 256, 0, stream>>>(attn, v, ctx);
}